// Round 8
// baseline (175.806 us; speedup 1.0000x reference)
//
#include <hip/hip_runtime.h>
#include <hip/hip_bf16.h>

// ---------------------------------------------------------------------------
// CollapsedPBFA: x->(qkv GEMM)->cheb-kernelized linear attention->out GEMM
// R8: GEMM moved to BK=32: 64B LDS row stride = conflict-free b128 reads
//     (no swizzle), 3-buf x 24KB = 72KB LDS -> 2 blocks/CU, distance-2
//     prefetch with vmcnt(3), 2 quadrant phases per tile.
//     kv_partial / kv_reduce / attn unchanged (passed, absmax 32).
// ---------------------------------------------------------------------------

#define SEQ    4096
#define BATCH  2
#define DMODEL 1024
#define NH     16
#define DH     64
#define MD     11
#define NCH    8
#define CHUNK  512   // SEQ / NCH

typedef __attribute__((ext_vector_type(8)))  short  short8;
typedef __attribute__((ext_vector_type(4)))  short  s16x4;
typedef __attribute__((ext_vector_type(8)))  __bf16 bf16x8;
typedef __attribute__((ext_vector_type(4)))  float  f32x4;

__device__ __forceinline__ short f2bf(float f) {
  union { float f; unsigned u; } c; c.f = f;
  unsigned r = c.u + 0x7FFFu + ((c.u >> 16) & 1u);
  return (short)(r >> 16);
}
__device__ __forceinline__ float bf2f(short h) {
  union { unsigned u; float f; } c; c.u = ((unsigned)(unsigned short)h) << 16;
  return c.f;
}

__device__ __forceinline__ f32x4 mfma16(short8 a, short8 b, f32x4 c) {
  return __builtin_amdgcn_mfma_f32_16x16x32_bf16(
      __builtin_bit_cast(bf16x8, a), __builtin_bit_cast(bf16x8, b), c, 0, 0, 0);
}

typedef const __attribute__((address_space(1))) void* gvp;
typedef __attribute__((address_space(3))) void* lvp;
// Async global->LDS, 16B per lane: lane i lands at (uniform dst) + 16*i.
__device__ __forceinline__ void gload16(const void* g, void* l) {
  __builtin_amdgcn_global_load_lds((gvp)g, (lvp)l, 16, 0, 0);
}

// ---------------------------------------------------------------------------
// f32 -> bf16 elementwise convert (vectorized).
// ---------------------------------------------------------------------------
__global__ __launch_bounds__(256) void to_bf16(const float* __restrict__ src,
                                               short* __restrict__ dst, int n4) {
  int i = blockIdx.x * 256 + threadIdx.x;
  if (i < n4) {
    f32x4 v = ((const f32x4*)src)[i];
    s16x4 o;
#pragma unroll
    for (int q = 0; q < 4; ++q) o[q] = f2bf(v[q]);
    ((s16x4*)dst)[i] = o;
  }
}

// ---------------------------------------------------------------------------
// GEMM: C[M][N] = A[M][K] * B[N][K]^T, A/B bf16.
// Tile 256x128, BK=32, 512 threads = 8 waves (wm=w>>1 in 0..3, wn=w&1),
// per-wave 64x64. 3-buffer LDS rotation (72KB -> 2 blocks/CU), distance-2
// staging (3 gload16/wave/tile), vmcnt(3) + 1 barrier per tile.
// BK=32 -> 64B row stride -> b128 frag reads hit 8 bank-quads = minimum
// aliasing: conflict-free without swizzle.
// Requires: M%256==0, N%128==0, K%32==0, NT>=3, grid%8==0.
// ---------------------------------------------------------------------------
template <typename SC>
__global__ __launch_bounds__(512, 4) void gemm256(const short* __restrict__ A,
                                                  const short* __restrict__ B,
                                                  SC* __restrict__ C,
                                                  int M, int N, int K) {
  // per buf: A 256x32 (8192 sh) + B 128x32 (4096 sh) = 12288 sh; 3 bufs.
  __shared__ short lds[36864];

  const int tid  = threadIdx.x;
  const int lane = tid & 63;
  const int w    = tid >> 6;        // 0..7
  const int wm   = w >> 1;          // 0..3 (64-row strip)
  const int wn   = w & 1;           // 0..1 (64-col strip)
  const int g    = lane >> 4;       // 0..3
  const int r    = lane & 15;       // 0..15

  const int nbn = N >> 7;
  int bid = blockIdx.x;
  {  // bijective XCD swizzle (gridDim.x % 8 == 0 for our shapes)
    const int cpx = gridDim.x >> 3;
    bid = (bid & 7) * cpx + (bid >> 3);
  }
  const int brow = (bid / nbn) << 8;
  const int bcol = (bid % nbn) << 7;
  const int NT   = K >> 5;

  // staging lane geometry: one gload16 issue covers 16 rows x 32 cols.
  const int lr = lane >> 2;        // 0..15 row within strip
  const int lc = (lane & 3) * 8;   // 16B chunk within row (shorts)

  f32x4 acc[4][4];
#pragma unroll
  for (int mi = 0; mi < 4; ++mi)
#pragma unroll
    for (int ni = 0; ni < 4; ++ni) acc[mi][ni] = (f32x4){0.f, 0.f, 0.f, 0.f};

  // per-wave global row bases (constant across tiles)
  const short* gA0 = A + (size_t)(brow + 0   + w * 16 + lr) * K + lc;
  const short* gA1 = A + (size_t)(brow + 128 + w * 16 + lr) * K + lc;
  const short* gB0 = B + (size_t)(bcol +       w * 16 + lr) * K + lc;

  auto STAGE = [&](int buf, int t) {
    const int k0 = t << 5;
    short* ab = &lds[buf * 12288];
    short* bb = &lds[buf * 12288 + 8192];
    gload16(gA0 + k0, ab + (w * 16) * 32);
    gload16(gA1 + k0, ab + (128 + w * 16) * 32);
    gload16(gB0 + k0, bb + (w * 16) * 32);
  };

  // ---- prologue: 2 tiles in flight ----
  STAGE(0, 0);
  STAGE(1, 1);
  asm volatile("s_waitcnt vmcnt(3)\n\ts_barrier" ::: "memory");

  for (int kt = 0; kt < NT; ++kt) {
    const int cur = kt % 3;
    const short* ab = &lds[cur * 12288];
    const short* bb = &lds[cur * 12288 + 8192];

    // stage tile kt+2 into the buffer freed one iteration ago
    if (kt + 2 < NT) STAGE((kt + 2) % 3, kt + 2);

    short8 av[4], bv[4];
#pragma unroll
    for (int mi = 0; mi < 4; ++mi)
      av[mi] = *(const short8*)(ab + (wm * 64 + mi * 16 + r) * 32 + g * 8);
#pragma unroll
    for (int ni = 0; ni < 2; ++ni)
      bv[ni] = *(const short8*)(bb + (wn * 64 + ni * 16 + r) * 32 + g * 8);

    __builtin_amdgcn_s_setprio(1);
#pragma unroll
    for (int mi = 0; mi < 4; ++mi)
#pragma unroll
      for (int ni = 0; ni < 2; ++ni)
        acc[mi][ni] = mfma16(av[mi], bv[ni], acc[mi][ni]);
    __builtin_amdgcn_s_setprio(0);

#pragma unroll
    for (int ni = 2; ni < 4; ++ni)
      bv[ni] = *(const short8*)(bb + (wn * 64 + ni * 16 + r) * 32 + g * 8);

    __builtin_amdgcn_s_setprio(1);
#pragma unroll
    for (int mi = 0; mi < 4; ++mi)
#pragma unroll
      for (int ni = 2; ni < 4; ++ni)
        acc[mi][ni] = mfma16(av[mi], bv[ni], acc[mi][ni]);
    __builtin_amdgcn_s_setprio(0);

    if (kt + 1 < NT) {
      if (kt + 2 < NT) asm volatile("s_waitcnt vmcnt(3)\n\ts_barrier" ::: "memory");
      else             asm volatile("s_waitcnt vmcnt(0)\n\ts_barrier" ::: "memory");
    }
  }

#pragma unroll
  for (int mi = 0; mi < 4; ++mi) {
    const int row0 = brow + wm * 64 + mi * 16 + g * 4;
#pragma unroll
    for (int ni = 0; ni < 4; ++ni) {
      const int col = bcol + wn * 64 + ni * 16 + r;
#pragma unroll
      for (int rr = 0; rr < 4; ++rr) {
        float v = acc[mi][ni][rr];
        if constexpr (sizeof(SC) == 2) C[(size_t)(row0 + rr) * N + col] = f2bf(v);
        else                           C[(size_t)(row0 + rr) * N + col] = v;
      }
    }
  }
}

// ---------------------------------------------------------------------------
// kv partial: block = (bh, chunk of 512 s-rows). Stage k~/v transposed into
// chunk-resident LDS once, loop active m over the resident tile.
// ---------------------------------------------------------------------------
__global__ __launch_bounds__(256) void kv_partial(const short* __restrict__ qkv,
                                                  const float* __restrict__ beta,
                                                  short* __restrict__ partial) {
  const int bh = blockIdx.x / NCH;
  const int ch = blockIdx.x % NCH;
  const int b  = bh >> 4, h = bh & 15;

  __shared__ short kT[64][522];   // [kd][s], stride 261 dw
  __shared__ short vT[64][522];   // [dv][s]

  const int tid  = threadIdx.x;
  const int lane = tid & 63;
  const int w    = tid >> 6;
  const int g    = lane >> 4;
  const int r    = lane & 15;

  const int srl  = tid >> 2;
  const int part = tid & 3;
  const size_t base = (size_t)b * SEQ * 3072 + (size_t)(ch * CHUNK) * 3072;
  const int kcol = DMODEL     + h * 64 + part * 16;
  const int vcol = 2 * DMODEL + h * 64 + part * 16;

#pragma unroll
  for (int ss = 0; ss < CHUNK; ss += 64) {
    const short* gk = qkv + base + (size_t)(ss + srl) * 3072 + kcol;
    const short* gv = qkv + base + (size_t)(ss + srl) * 3072 + vcol;
    short8 k0 = *(const short8*)gk;
    short8 k1 = *(const short8*)(gk + 8);
    short8 v0 = *(const short8*)gv;
    short8 v1 = *(const short8*)(gv + 8);
    const int sidx = ss + srl;
#pragma unroll
    for (int q = 0; q < 8; ++q) {
      kT[part * 16 + q][sidx]     = f2bf(fminf(fmaxf(bf2f(k0[q]) * 0.125f, -1.f), 1.f));
      kT[part * 16 + 8 + q][sidx] = f2bf(fminf(fmaxf(bf2f(k1[q]) * 0.125f, -1.f), 1.f));
      vT[part * 16 + q][sidx]     = v0[q];
      vT[part * 16 + 8 + q][sidx] = v1[q];
    }
  }
  __syncthreads();

  for (int m = 0; m < MD; ++m) {
    if (beta[h * MD + m] == 0.f) continue;

    f32x4 acc[4];
#pragma unroll
    for (int j = 0; j < 4; ++j) acc[j] = (f32x4){0.f, 0.f, 0.f, 0.f};

#pragma unroll 1
    for (int kt = 0; kt < CHUNK / 32; ++kt) {
      const int s0 = kt * 32 + g * 8;
      short8 af;
      if (m == 0) {
#pragma unroll
        for (int q = 0; q < 8; ++q) af[q] = (short)0x3F80;
      } else {
        short8 xs = *(const short8*)&kT[w * 16 + r][s0];
        float Tp[8], Tc[8];
#pragma unroll
        for (int q = 0; q < 8; ++q) { float xv = bf2f(xs[q]); Tp[q] = 1.f; Tc[q] = xv; }
        for (int mm = 1; mm < m; ++mm) {
#pragma unroll
          for (int q = 0; q < 8; ++q) {
            float xv = bf2f(xs[q]);
            float Tn = 2.f * xv * Tc[q] - Tp[q];
            Tp[q] = Tc[q]; Tc[q] = Tn;
          }
        }
#pragma unroll
        for (int q = 0; q < 8; ++q) af[q] = f2bf(Tc[q]);
      }
#pragma unroll
      for (int j = 0; j < 4; ++j) {
        short8 bfg = *(const short8*)&vT[j * 16 + r][s0];
        acc[j] = mfma16(af, bfg, acc[j]);
      }
    }

    short* po = partial + ((size_t)(bh * MD + m) * NCH + ch) * 4096;
#pragma unroll
    for (int j = 0; j < 4; ++j) {
      const int kd = w * 16 + g * 4;
      const int dv = j * 16 + r;
#pragma unroll
      for (int rr = 0; rr < 4; ++rr) po[(size_t)(kd + rr) * 64 + dv] = f2bf(acc[j][rr]);
    }
  }
}

// ---------------------------------------------------------------------------
// reduce partials -> kvbuf f32.
// ---------------------------------------------------------------------------
__global__ __launch_bounds__(256) void kv_reduce(const short* __restrict__ partial,
                                                 const float* __restrict__ beta,
                                                 float* __restrict__ kv) {
  const int m  = blockIdx.x % MD;
  const int bh = blockIdx.x / MD;
  const int h  = bh & 15;
  if (beta[h * MD + m] == 0.f) return;

  const int tid = threadIdx.x;
  const short* src = partial + (size_t)(bh * MD + m) * NCH * 4096;
  float* dst = kv + (size_t)(bh * MD + m) * 4096;
#pragma unroll
  for (int e0 = 0; e0 < 4096; e0 += 256) {
    float s = 0.f;
#pragma unroll
    for (int c = 0; c < NCH; ++c) s += bf2f(src[c * 4096 + e0 + tid]);
    dst[e0 + tid] = s;
  }
}

// ---------------------------------------------------------------------------
// attn: per (b,h,256 s-rows); kv staged bf16-transposed in LDS.
// ---------------------------------------------------------------------------
__global__ __launch_bounds__(256) void attn_kernel(const short* __restrict__ qkv,
                                                   const float* __restrict__ beta,
                                                   const float* __restrict__ kv,
                                                   short* __restrict__ attn) {
  const int bid  = blockIdx.x;
  const int bh   = bid >> 4;
  const int sblk = bid & 15;
  const int b    = bh >> 4, h = bh & 15;

  __shared__ short kvT[64][744];

  const int tid  = threadIdx.x;
  const int lane = tid & 63;
  const int w    = tid >> 6;
  const int g    = lane >> 4;
  const int r    = lane & 15;

  float betav[MD];
#pragma unroll
  for (int mm = 0; mm < MD; ++mm) betav[mm] = beta[h * MD + mm];

  {
    int am = 0;
#pragma unroll
    for (int mm = 0; mm < MD; ++mm) {
      if (betav[mm] != 0.f) {
        const float* src = kv + (size_t)(bh * MD + mm) * 4096;
        for (int e = tid; e < 4096; e += 256) {
          const int kd = e >> 6, dv = e & 63;
          kvT[dv][am * 64 + kd] = f2bf(src[e]);
        }
        ++am;
      }
    }
  }
  __syncthreads();

  const size_t qbase = (size_t)b * SEQ * 3072 + (size_t)h * 64;

#pragma unroll 1
  for (int st = 0; st < 4; ++st) {
    const int srow = sblk * 256 + w * 64 + st * 16 + r;
    const short* gq = qkv + qbase + (size_t)srow * 3072;
    short8 q0 = *(const short8*)(gq + g * 8);
    short8 q1 = *(const short8*)(gq + 32 + g * 8);
    float x[16];
#pragma unroll
    for (int q = 0; q < 8; ++q) {
      x[q]     = fminf(fmaxf(bf2f(q0[q]) * 0.125f, -1.f), 1.f);
      x[8 + q] = fminf(fmaxf(bf2f(q1[q]) * 0.125f, -1.f), 1.f);
    }
    float Tp[16], Tc[16];
#pragma unroll
    for (int q = 0; q < 16; ++q) { Tp[q] = 1.f; Tc[q] = x[q]; }
    f32x4 acc[4];
#pragma unroll
    for (int j = 0; j < 4; ++j) acc[j] = (f32x4){0.f, 0.f, 0.f, 0.f};

    int am = 0;
#pragma unroll
    for (int mt = 0; mt < MD; ++mt) {
      if (mt >= 2) {
#pragma unroll
        for (int q = 0; q < 16; ++q) {
          float Tn = 2.f * x[q] * Tc[q] - Tp[q];
          Tp[q] = Tc[q]; Tc[q] = Tn;
        }
      }
      if (betav[mt] != 0.f) {
        const float bm = betav[mt];
        short8 a0, a1;
        if (mt == 0) {
          const short one = f2bf(bm);
#pragma unroll
          for (int q = 0; q < 8; ++q) { a0[q] = one; a1[q] = one; }
        } else {
#pragma unroll
          for (int q = 0; q < 8; ++q) {
            a0[q] = f2bf(bm * Tc[q]);
            a1[q] = f2bf(bm * Tc[8 + q]);
          }
        }
#pragma unroll
        for (int j = 0; j < 4; ++j) {
          short8 b0 = *(const short8*)&kvT[j * 16 + r][am * 64 + g * 8];
          acc[j] = mfma16(a0, b0, acc[j]);
          short8 b1 = *(const short8*)&kvT[j * 16 + r][am * 64 + 32 + g * 8];
          acc[j] = mfma16(a1, b1, acc[j]);
        }
        ++am;
      }
    }

#pragma unroll
    for (int j = 0; j < 4; ++j) {
      const int col = h * 64 + j * 16 + r;
#pragma unroll
      for (int rr = 0; rr < 4; ++rr) {
        const int sr = sblk * 256 + w * 64 + st * 16 + g * 4 + rr;
        attn[(size_t)(b * SEQ + sr) * DMODEL + col] = f2bf(acc[j][rr]);
      }
    }
  }
}

// ---------------------------------------------------------------------------
extern "C" void kernel_launch(void* const* d_in, const int* in_sizes, int n_in,
                              void* d_out, int out_size, void* d_ws, size_t ws_size,
                              hipStream_t stream) {
  const float* x     = (const float*)d_in[0];
  const float* w_in  = (const float*)d_in[1];
  const float* w_out = (const float*)d_in[2];
  const float* beta  = (const float*)d_in[3];
  float* out = (float*)d_out;

  char* ws = (char*)d_ws;
  short* qkv     = (short*)ws;                    // 50,331,648 B
  float* kvbuf   = (float*)(ws + 50331648);       //  5,767,168 B
  short* w_inb   = (short*)(ws + 56098816);       //  6,291,456 B
  short* w_outb  = (short*)(ws + 62390272);       //  2,097,152 B
  char*  regionU = ws + 64487424;                 // xb / partial / attn union
  short* xb      = (short*)regionU;
  short* partial = (short*)regionU;
  short* attn    = (short*)regionU;

  const int Mrows = BATCH * SEQ;  // 8192

  // 0) pre-convert f32 -> bf16
  to_bf16<<<dim3(8192), dim3(256), 0, stream>>>(x,     xb,     2097152);
  to_bf16<<<dim3(3072), dim3(256), 0, stream>>>(w_in,  w_inb,   786432);
  to_bf16<<<dim3(1024), dim3(256), 0, stream>>>(w_out, w_outb,  262144);

  // 1) qkv = x @ w_in^T        (8192 x 3072 x 1024): 32 x 24 = 768 blocks
  gemm256<short><<<dim3((Mrows / 256) * (3 * DMODEL / 128)), dim3(512), 0, stream>>>(
      xb, w_inb, qkv, Mrows, 3 * DMODEL, DMODEL);

  // 2) kv partials over s-chunks, then reduce
  kv_partial<<<dim3(BATCH * NH * NCH), dim3(256), 0, stream>>>(qkv, beta, partial);
  kv_reduce<<<dim3(BATCH * NH * MD), dim3(256), 0, stream>>>(partial, beta, kvbuf);

  // 3) attn = sum_m beta_m T_m(q) @ kv_m
  attn_kernel<<<dim3(32 * 16), dim3(256), 0, stream>>>(qkv, beta, kvbuf, attn);

  // 4) out = attn @ w_out^T    (8192 x 1024 x 1024): 32 x 8 = 256 blocks
  gemm256<float><<<dim3((Mrows / 256) * (DMODEL / 128)), dim3(512), 0, stream>>>(
      attn, w_outb, out, Mrows, DMODEL, DMODEL);
}